// Round 4
// baseline (224.117 us; speedup 1.0000x reference)
//
#include <hip/hip_runtime.h>

#define NN  512    // data grid / coefficient count per axis
#define NE  1024   // eval points per axis
#define NBC 64     // batch * channels
#define WH  8      // truncated-inverse half width
#define WT  17     // 2*WH+1 taps

// ================= compile-time table generation =================
// Mirrors the reference: x = float32 linspace(-1,1,512); knots via float32
// cumsum sliding mean; basis via de Boor in double; banded LU in double;
// then the TRUNCATED INVERSE band Gb[j][d] = Ainv[j][j-8+d] via windowed
// column solves (boundary columns exact + interior Toeplitz column).

struct Tables {
  float Gb[NN][WT];      // truncated A^-1 band, zero-padded (row-indexed)
  float GbT[WT][NN];     // transposed: GbT[d][i] = Gb[i][d]  (coalesced tap loads)
  int   espan[NE];
  float ebas[NE * 4];    // float4-aligned
};

constexpr int cfindspan(double u, const float* t) {
  if (u >= (double)t[NN]) return NN - 1;          // t[512] == 1.0
  int lo = 3, hi = NN - 1;
  while (lo < hi) {
    int mid = (lo + hi + 1) >> 1;
    if ((double)t[mid] <= u) lo = mid; else hi = mid - 1;
  }
  return lo;
}

constexpr void cdeboor4(double u, const float* t, int s, double* N) {
  double left[4] = {}, right[4] = {};
  N[0] = 1.0; N[1] = 0.0; N[2] = 0.0; N[3] = 0.0;
  for (int d = 1; d <= 3; ++d) {
    left[d]  = u - (double)t[s + 1 - d];
    right[d] = (double)t[s + d] - u;
    double saved = 0.0;
    for (int r = 0; r < d; ++r) {
      double temp = N[r] / (right[r + 1] + left[d - r]);
      N[r] = saved + right[r + 1] * temp;
      saved = left[d - r] * temp;
    }
    N[d] = saved;
  }
}

constexpr Tables make_tables() {
  Tables T{};
  float x[NN] = {};
  for (int i = 0; i < NN; ++i) x[i] = (float)(-1.0 + (2.0 * i) / 511.0);
  x[0] = -1.0f; x[NN - 1] = 1.0f;
  float t[NN + 4] = {};
  {
    float cs[NN + 1] = {};
    for (int i = 0; i < NN; ++i) cs[i + 1] = cs[i] + x[i];
    for (int i = 0; i < NN - 4; ++i) t[4 + i] = (cs[4 + i] - cs[1 + i]) / 3.0f;
    for (int i = 0; i < 4; ++i) { t[i] = -1.0f; t[NN + i] = 1.0f; }
  }
  double W[NN][7] = {};
  for (int r = 0; r < NN; ++r) {
    double u = (double)x[r];
    int s = cfindspan(u, t);
    double N[4] = {};
    cdeboor4(u, t, s, N);
    for (int dd = 0; dd < 4; ++dd) W[r][s - r + dd] += N[dd];
  }
  for (int r = 0; r < NN; ++r) {
    double rd = 1.0 / W[r][3];
    for (int k = 1; k <= 3; ++k) {
      if (r + k < NN) {
        double l = W[r + k][3 - k] * rd;
        W[r + k][3 - k] = l;
        for (int cc = 1; cc <= 3; ++cc) W[r + k][3 - k + cc] -= l * W[r][3 + cc];
      }
    }
  }
  // truncated inverse band
  double tv[WT] = {};
  for (int pass = 0; pass < 3; ++pass) {
    const int ylo = (pass == 0) ? 0 : (pass == 1) ? 480 : 256;
    const int yhi = (pass == 0) ? 32 : (pass == 1) ? 512 : 257;
    for (int y = ylo; y < yhi; ++y) {
      double wv[21] = {};
      int rend = y + 20; if (rend > NN - 1) rend = NN - 1;
      wv[0] = 1.0;
      for (int r = y + 1; r <= rend; ++r) {
        double acc = 0.0;
        if (r - 1 >= y) acc += W[r][2] * wv[r - 1 - y];
        if (r - 2 >= y) acc += W[r][1] * wv[r - 2 - y];
        if (r - 3 >= y) acc += W[r][0] * wv[r - 3 - y];
        wv[r - y] = -acc;
      }
      double g[29] = {};
      int glo = y - WH; if (glo < 0) glo = 0;
      for (int r = rend; r >= glo; --r) {
        double acc = (r >= y) ? wv[r - y] : 0.0;
        if (r + 1 <= rend) acc -= W[r][4] * g[r + 1 - (y - WH)];
        if (r + 2 <= rend) acc -= W[r][5] * g[r + 2 - (y - WH)];
        if (r + 3 <= rend) acc -= W[r][6] * g[r + 3 - (y - WH)];
        g[r - (y - WH)] = acc / W[r][3];
      }
      if (pass == 2) {
        for (int d = 0; d < WT; ++d) tv[d] = g[16 - d];
      } else {
        int jlo = y - WH; if (jlo < 0) jlo = 0;
        int jhi = y + WH; if (jhi > NN - 1) jhi = NN - 1;
        for (int j = jlo; j <= jhi; ++j) {
          const bool bdry = (pass == 0) ? (j < 24) : (j >= 488);
          if (bdry) T.Gb[j][y - j + WH] = (float)g[j - (y - WH)];
        }
      }
    }
  }
  for (int j = 24; j < 488; ++j)
    for (int d = 0; d < WT; ++d) T.Gb[j][d] = (float)tv[d];
  for (int d = 0; d < WT; ++d)
    for (int i = 0; i < NN; ++i) T.GbT[d][i] = T.Gb[i][d];
  // eval-point basis
  for (int i = 0; i < NE; ++i) {
    float xe = (float)(-1.0 + (2.0 * i) / 1023.0);
    if (i == 0) xe = -1.0f;
    if (i == NE - 1) xe = 1.0f;
    double u = (double)xe;
    int s = cfindspan(u, t);
    double N[4] = {};
    cdeboor4(u, t, s, N);
    T.espan[i] = s;
    T.ebas[i * 4 + 0] = (float)N[0];
    T.ebas[i * 4 + 1] = (float)N[1];
    T.ebas[i * 4 + 2] = (float)N[2];
    T.ebas[i * 4 + 3] = (float)N[3];
  }
  return T;
}

__constant__ Tables g_tab = make_tables();

// ------------- K1: contract y (17-tap band), fused transpose -------------
// S2T[bc][j][x] = sum_d Gb[j][d] * Z[bc][x][j-8+d]

__global__ __launch_bounds__(256) void k_conv1(const float* __restrict__ Z,
                                               float* __restrict__ S2T) {
  const int xt = blockIdx.x * 64;
  const int jt = blockIdx.y * 64;
  const int bc = blockIdx.z;
  const float* __restrict__ src = Z + (size_t)bc * (NN * NN);
  __shared__ float in[64][88];   // y-window [jt-8, jt+72)
  __shared__ float tr[64][65];   // transpose buffer (+1 pad)
  const int tid = threadIdx.x;
  const int jqi = tid & 15;
  float c[4][WT];
  #pragma unroll
  for (int q = 0; q < 4; ++q)
    #pragma unroll
    for (int d = 0; d < WT; ++d)
      c[q][d] = g_tab.Gb[jt + jqi * 4 + q][d];
  for (int u = tid; u < 64 * 20; u += 256) {
    const int r = u / 20, c4 = u % 20;
    const int y0 = jt - 8 + c4 * 4;
    float4 v;
    if (y0 >= 0 && y0 + 4 <= NN) {
      v = *(const float4*)&src[(size_t)(xt + r) * NN + y0];
    } else {
      float e0 = (y0 + 0 >= 0 && y0 + 0 < NN) ? src[(size_t)(xt + r) * NN + y0 + 0] : 0.f;
      float e1 = (y0 + 1 >= 0 && y0 + 1 < NN) ? src[(size_t)(xt + r) * NN + y0 + 1] : 0.f;
      float e2 = (y0 + 2 >= 0 && y0 + 2 < NN) ? src[(size_t)(xt + r) * NN + y0 + 2] : 0.f;
      float e3 = (y0 + 3 >= 0 && y0 + 3 < NN) ? src[(size_t)(xt + r) * NN + y0 + 3] : 0.f;
      v = make_float4(e0, e1, e2, e3);
    }
    *(float4*)&in[r][c4 * 4] = v;
  }
  __syncthreads();
  #pragma unroll
  for (int p = 0; p < 4; ++p) {
    const int xl = (tid >> 4) + p * 16;
    float w[20];
    #pragma unroll
    for (int e = 0; e < 5; ++e)
      *(float4*)&w[e * 4] = *(const float4*)&in[xl][jqi * 4 + e * 4];
    float4 a = make_float4(0.f, 0.f, 0.f, 0.f);
    #pragma unroll
    for (int d = 0; d < WT; ++d) {
      a.x += c[0][d] * w[0 + d];
      a.y += c[1][d] * w[1 + d];
      a.z += c[2][d] * w[2 + d];
      a.w += c[3][d] * w[3 + d];
    }
    tr[jqi * 4 + 0][xl] = a.x;
    tr[jqi * 4 + 1][xl] = a.y;
    tr[jqi * 4 + 2][xl] = a.z;
    tr[jqi * 4 + 3][xl] = a.w;
  }
  __syncthreads();
  float* __restrict__ dst = S2T + (size_t)bc * (NN * NN);
  for (int u = tid; u < 64 * 16; u += 256) {
    const int jr = u >> 4, x4 = (u & 15) * 4;
    float4 v = make_float4(tr[jr][x4 + 0], tr[jr][x4 + 1], tr[jr][x4 + 2], tr[jr][x4 + 3]);
    *(float4*)&dst[(size_t)(jt + jr) * NN + xt + x4] = v;
  }
}

// ------------- K2: fused x-band + evaluation -------------
// R[x]  = sum_q wy[q] * S2T[sy-3+q][x]          (combine 4 rows)
// H[p]  = sum_d Gb[p][d] * R[p-8+d]             (17-tap x band)
// out[y][x] = 4-tap combination of H

__global__ __launch_bounds__(256) void k_eval2(const float* __restrict__ S2T,
                                               float* __restrict__ out) {
  const int y = blockIdx.x;    // output row f
  const int bc = blockIdx.y;
  const float* __restrict__ S = S2T + (size_t)bc * (NN * NN);
  __shared__ float R[NN + 16];   // R[8+x]; halo zeros at [0..7], [520..527]
  __shared__ float H[NN];
  const int tid = threadIdx.x;
  const int sy = g_tab.espan[y];
  const float4 wy = *(const float4*)&g_tab.ebas[y * 4];
  if (tid < 16) R[(tid & 7) + (tid >> 3) * (NN + 8)] = 0.f;
  #pragma unroll
  for (int pp = 0; pp < 2; ++pp) {
    const int p = tid + pp * 256;
    R[8 + p] = wy.x * S[(size_t)(sy - 3) * NN + p]
             + wy.y * S[(size_t)(sy - 2) * NN + p]
             + wy.z * S[(size_t)(sy - 1) * NN + p]
             + wy.w * S[(size_t)(sy)     * NN + p];
  }
  __syncthreads();
  #pragma unroll
  for (int pp = 0; pp < 2; ++pp) {
    const int p = tid + pp * 256;
    float acc = 0.f;
    #pragma unroll
    for (int d = 0; d < WT; ++d) acc += g_tab.GbT[d][p] * R[p + d];
    H[p] = acc;
  }
  __syncthreads();
  float* __restrict__ O = out + ((size_t)bc * NE + y) * NE;
  const int x0 = tid * 4;
  float4 o;
  #pragma unroll
  for (int e = 0; e < 4; ++e) {
    const int x = x0 + e;
    const int sx = g_tab.espan[x];
    const float4 wx = *(const float4*)&g_tab.ebas[x * 4];
    (&o.x)[e] = wx.x * H[sx - 3] + wx.y * H[sx - 2] + wx.z * H[sx - 1] + wx.w * H[sx];
  }
  *(float4*)&O[x0] = o;
}

// ---------------- host launcher ----------------

extern "C" void kernel_launch(void* const* d_in, const int* in_sizes, int n_in,
                              void* d_out, int out_size, void* d_ws, size_t ws_size,
                              hipStream_t stream) {
  (void)in_sizes; (void)n_in; (void)out_size; (void)ws_size;
  const float* Z = (const float*)d_in[0];
  float* out = (float*)d_out;
  float* S2T = (float*)d_ws;      // 64 MB (must not alias out: eval reads it while writing out)

  k_conv1<<<dim3(8, 8, NBC), 256, 0, stream>>>(Z,   S2T);  // contract y + transpose
  k_eval2<<<dim3(NE, NBC),   256, 0, stream>>>(S2T, out);  // fused x-band + eval
}

// Round 5
// 148.691 us; speedup vs baseline: 1.5073x; 1.5073x over previous
//
#include <hip/hip_runtime.h>

#define NN  512    // data grid / coefficient count per axis
#define NE  1024   // eval points per axis
#define NBC 64     // batch * channels
#define WH  8      // truncated-inverse half width
#define WT  17     // 2*WH+1 taps
#define YT  16     // y-tile per eval block

// ================= compile-time table generation =================
// Mirrors the reference: x = float32 linspace(-1,1,512); knots via float32
// cumsum sliding mean; basis via de Boor in double; banded LU in double;
// then the TRUNCATED INVERSE band Gb[j][d] = Ainv[j][j-8+d] via windowed
// column solves (boundary columns exact + interior Toeplitz column).

struct Tables {
  float Gb[NN][WT];      // truncated A^-1 band, zero-padded (row-indexed)
  int   espan[NE];
  float ebas[NE * 4];    // float4-aligned
};

constexpr int cfindspan(double u, const float* t) {
  if (u >= (double)t[NN]) return NN - 1;          // t[512] == 1.0
  int lo = 3, hi = NN - 1;
  while (lo < hi) {
    int mid = (lo + hi + 1) >> 1;
    if ((double)t[mid] <= u) lo = mid; else hi = mid - 1;
  }
  return lo;
}

constexpr void cdeboor4(double u, const float* t, int s, double* N) {
  double left[4] = {}, right[4] = {};
  N[0] = 1.0; N[1] = 0.0; N[2] = 0.0; N[3] = 0.0;
  for (int d = 1; d <= 3; ++d) {
    left[d]  = u - (double)t[s + 1 - d];
    right[d] = (double)t[s + d] - u;
    double saved = 0.0;
    for (int r = 0; r < d; ++r) {
      double temp = N[r] / (right[r + 1] + left[d - r]);
      N[r] = saved + right[r + 1] * temp;
      saved = left[d - r] * temp;
    }
    N[d] = saved;
  }
}

constexpr Tables make_tables() {
  Tables T{};
  float x[NN] = {};
  for (int i = 0; i < NN; ++i) x[i] = (float)(-1.0 + (2.0 * i) / 511.0);
  x[0] = -1.0f; x[NN - 1] = 1.0f;
  float t[NN + 4] = {};
  {
    float cs[NN + 1] = {};
    for (int i = 0; i < NN; ++i) cs[i + 1] = cs[i] + x[i];
    for (int i = 0; i < NN - 4; ++i) t[4 + i] = (cs[4 + i] - cs[1 + i]) / 3.0f;
    for (int i = 0; i < 4; ++i) { t[i] = -1.0f; t[NN + i] = 1.0f; }
  }
  double W[NN][7] = {};
  for (int r = 0; r < NN; ++r) {
    double u = (double)x[r];
    int s = cfindspan(u, t);
    double N[4] = {};
    cdeboor4(u, t, s, N);
    for (int dd = 0; dd < 4; ++dd) W[r][s - r + dd] += N[dd];
  }
  for (int r = 0; r < NN; ++r) {
    double rd = 1.0 / W[r][3];
    for (int k = 1; k <= 3; ++k) {
      if (r + k < NN) {
        double l = W[r + k][3 - k] * rd;
        W[r + k][3 - k] = l;
        for (int cc = 1; cc <= 3; ++cc) W[r + k][3 - k + cc] -= l * W[r][3 + cc];
      }
    }
  }
  // truncated inverse band
  double tv[WT] = {};
  for (int pass = 0; pass < 3; ++pass) {
    const int ylo = (pass == 0) ? 0 : (pass == 1) ? 480 : 256;
    const int yhi = (pass == 0) ? 32 : (pass == 1) ? 512 : 257;
    for (int y = ylo; y < yhi; ++y) {
      double wv[21] = {};
      int rend = y + 20; if (rend > NN - 1) rend = NN - 1;
      wv[0] = 1.0;
      for (int r = y + 1; r <= rend; ++r) {
        double acc = 0.0;
        if (r - 1 >= y) acc += W[r][2] * wv[r - 1 - y];
        if (r - 2 >= y) acc += W[r][1] * wv[r - 2 - y];
        if (r - 3 >= y) acc += W[r][0] * wv[r - 3 - y];
        wv[r - y] = -acc;
      }
      double g[29] = {};
      int glo = y - WH; if (glo < 0) glo = 0;
      for (int r = rend; r >= glo; --r) {
        double acc = (r >= y) ? wv[r - y] : 0.0;
        if (r + 1 <= rend) acc -= W[r][4] * g[r + 1 - (y - WH)];
        if (r + 2 <= rend) acc -= W[r][5] * g[r + 2 - (y - WH)];
        if (r + 3 <= rend) acc -= W[r][6] * g[r + 3 - (y - WH)];
        g[r - (y - WH)] = acc / W[r][3];
      }
      if (pass == 2) {
        for (int d = 0; d < WT; ++d) tv[d] = g[16 - d];
      } else {
        int jlo = y - WH; if (jlo < 0) jlo = 0;
        int jhi = y + WH; if (jhi > NN - 1) jhi = NN - 1;
        for (int j = jlo; j <= jhi; ++j) {
          const bool bdry = (pass == 0) ? (j < 24) : (j >= 488);
          if (bdry) T.Gb[j][y - j + WH] = (float)g[j - (y - WH)];
        }
      }
    }
  }
  for (int j = 24; j < 488; ++j)
    for (int d = 0; d < WT; ++d) T.Gb[j][d] = (float)tv[d];
  // eval-point basis
  for (int i = 0; i < NE; ++i) {
    float xe = (float)(-1.0 + (2.0 * i) / 1023.0);
    if (i == 0) xe = -1.0f;
    if (i == NE - 1) xe = 1.0f;
    double u = (double)xe;
    int s = cfindspan(u, t);
    double N[4] = {};
    cdeboor4(u, t, s, N);
    T.espan[i] = s;
    T.ebas[i * 4 + 0] = (float)N[0];
    T.ebas[i * 4 + 1] = (float)N[1];
    T.ebas[i * 4 + 2] = (float)N[2];
    T.ebas[i * 4 + 3] = (float)N[3];
  }
  return T;
}

__constant__ Tables g_tab = make_tables();

// ------------- K1: contract y (17-tap band), fused transpose -------------
// S2T[bc][j][x] = sum_d Gb[j][d] * Z[bc][x][j-8+d]

__global__ __launch_bounds__(256) void k_conv1(const float* __restrict__ Z,
                                               float* __restrict__ S2T) {
  const int xt = blockIdx.x * 64;
  const int jt = blockIdx.y * 64;
  const int bc = blockIdx.z;
  const float* __restrict__ src = Z + (size_t)bc * (NN * NN);
  __shared__ float in[64][88];   // y-window [jt-8, jt+72)
  __shared__ float tr[64][65];   // transpose buffer (+1 pad)
  const int tid = threadIdx.x;
  const int jqi = tid & 15;
  float c[4][WT];
  #pragma unroll
  for (int q = 0; q < 4; ++q)
    #pragma unroll
    for (int d = 0; d < WT; ++d)
      c[q][d] = g_tab.Gb[jt + jqi * 4 + q][d];
  for (int u = tid; u < 64 * 20; u += 256) {
    const int r = u / 20, c4 = u % 20;
    const int y0 = jt - 8 + c4 * 4;
    float4 v;
    if (y0 >= 0 && y0 + 4 <= NN) {
      v = *(const float4*)&src[(size_t)(xt + r) * NN + y0];
    } else {
      float e0 = (y0 + 0 >= 0 && y0 + 0 < NN) ? src[(size_t)(xt + r) * NN + y0 + 0] : 0.f;
      float e1 = (y0 + 1 >= 0 && y0 + 1 < NN) ? src[(size_t)(xt + r) * NN + y0 + 1] : 0.f;
      float e2 = (y0 + 2 >= 0 && y0 + 2 < NN) ? src[(size_t)(xt + r) * NN + y0 + 2] : 0.f;
      float e3 = (y0 + 3 >= 0 && y0 + 3 < NN) ? src[(size_t)(xt + r) * NN + y0 + 3] : 0.f;
      v = make_float4(e0, e1, e2, e3);
    }
    *(float4*)&in[r][c4 * 4] = v;
  }
  __syncthreads();
  #pragma unroll
  for (int p = 0; p < 4; ++p) {
    const int xl = (tid >> 4) + p * 16;
    float w[20];
    #pragma unroll
    for (int e = 0; e < 5; ++e)
      *(float4*)&w[e * 4] = *(const float4*)&in[xl][jqi * 4 + e * 4];
    float4 a = make_float4(0.f, 0.f, 0.f, 0.f);
    #pragma unroll
    for (int d = 0; d < WT; ++d) {
      a.x += c[0][d] * w[0 + d];
      a.y += c[1][d] * w[1 + d];
      a.z += c[2][d] * w[2 + d];
      a.w += c[3][d] * w[3 + d];
    }
    tr[jqi * 4 + 0][xl] = a.x;
    tr[jqi * 4 + 1][xl] = a.y;
    tr[jqi * 4 + 2][xl] = a.z;
    tr[jqi * 4 + 3][xl] = a.w;
  }
  __syncthreads();
  float* __restrict__ dst = S2T + (size_t)bc * (NN * NN);
  for (int u = tid; u < 64 * 16; u += 256) {
    const int jr = u >> 4, x4 = (u & 15) * 4;
    float4 v = make_float4(tr[jr][x4 + 0], tr[jr][x4 + 1], tr[jr][x4 + 2], tr[jr][x4 + 3]);
    *(float4*)&dst[(size_t)(jt + jr) * NN + xt + x4] = v;
  }
}

// ------------- K2: y-tiled fused x-band + evaluation -------------
// Per block: 16 output rows. Load the S2T row window ONCE into LDS, then
// per y-pair:  R[x] = 4-row combine;  H[p] = 17-tap band;  out = 4-tap H.
// Software-pipelined: R0; S; { H_k; S; out_k || R_{k+1}; S }.

__global__ __launch_bounds__(256) void k_eval3(const float* __restrict__ S2T,
                                               float* __restrict__ out) {
  const int y0 = blockIdx.x * YT;
  const int bc = blockIdx.y;
  const float* __restrict__ S = S2T + (size_t)bc * (NN * NN);
  __shared__ float rows[16][NN];        // 32 KB row window
  __shared__ float Rbuf[2][NN + 16];    // halo zeros at [0..7], [520..527]
  __shared__ float Hbuf[2][NN];
  const int tid = threadIdx.x;
  const int rlo = g_tab.espan[y0] - 3;  // window start (>=0; espan>=3)

  // cooperative load of 16 rows (rows beyond grid zeroed; never referenced)
  for (int u = tid; u < 16 * 128; u += 256) {
    const int rr = u >> 7, c4 = (u & 127) * 4;
    const int r = rlo + rr;
    float4 v = (r < NN) ? *(const float4*)&S[(size_t)r * NN + c4]
                        : make_float4(0.f, 0.f, 0.f, 0.f);
    *(float4*)&rows[rr][c4] = v;
  }
  if (tid < 32) {   // zero R halos once (never overwritten)
    const int buf = tid >> 4, off = tid & 15;
    const int idx = (off < 8) ? off : (NN + 8 + (off - 8));
    Rbuf[buf][idx] = 0.f;
  }

  // per-thread hoisted constants
  const int half = tid >> 7;            // which row of the pair (H phase)
  const int q4 = (tid & 127) * 4;       // H quad base
  float c[4][WT];
  #pragma unroll
  for (int qq = 0; qq < 4; ++qq)
    #pragma unroll
    for (int d = 0; d < WT; ++d)
      c[qq][d] = g_tab.Gb[q4 + qq][d];
  const int x0 = tid * 4;               // out quad base
  int sx[4]; float4 wx[4];
  #pragma unroll
  for (int e = 0; e < 4; ++e) {
    sx[e] = g_tab.espan[x0 + e];
    wx[e] = *(const float4*)&g_tab.ebas[(x0 + e) * 4];
  }
  const int p2 = tid * 2;               // R float2 base

  auto do_R = [&](int k) {
    #pragma unroll
    for (int hh = 0; hh < 2; ++hh) {
      const int y = y0 + 2 * k + hh;
      const int ry = g_tab.espan[y] - rlo;                   // 3..15 by construction
      const float4 wy = *(const float4*)&g_tab.ebas[y * 4];
      float2 r0 = *(const float2*)&rows[ry - 3][p2];
      float2 r1 = *(const float2*)&rows[ry - 2][p2];
      float2 r2 = *(const float2*)&rows[ry - 1][p2];
      float2 r3 = *(const float2*)&rows[ry    ][p2];
      float2 acc;
      acc.x = wy.x * r0.x + wy.y * r1.x + wy.z * r2.x + wy.w * r3.x;
      acc.y = wy.x * r0.y + wy.y * r1.y + wy.z * r2.y + wy.w * r3.y;
      *(float2*)&Rbuf[hh][8 + p2] = acc;
    }
  };

  __syncthreads();
  do_R(0);
  __syncthreads();
  #pragma unroll 1
  for (int k = 0; k < YT / 2; ++k) {
    {   // H for both rows of pair k (threads split by `half`)
      float w[20];
      #pragma unroll
      for (int e = 0; e < 5; ++e)
        *(float4*)&w[e * 4] = *(const float4*)&Rbuf[half][q4 + e * 4];
      float4 h = make_float4(0.f, 0.f, 0.f, 0.f);
      #pragma unroll
      for (int d = 0; d < WT; ++d) {
        h.x += c[0][d] * w[0 + d];
        h.y += c[1][d] * w[1 + d];
        h.z += c[2][d] * w[2 + d];
        h.w += c[3][d] * w[3 + d];
      }
      *(float4*)&Hbuf[half][q4] = h;
    }
    __syncthreads();
    if (k + 1 < YT / 2) do_R(k + 1);    // overlap next R with out
    {
      float* __restrict__ O = out + ((size_t)bc * NE + (y0 + 2 * k)) * NE;
      #pragma unroll
      for (int hh = 0; hh < 2; ++hh) {
        float4 o;
        #pragma unroll
        for (int e = 0; e < 4; ++e) {
          (&o.x)[e] = wx[e].x * Hbuf[hh][sx[e] - 3]
                    + wx[e].y * Hbuf[hh][sx[e] - 2]
                    + wx[e].z * Hbuf[hh][sx[e] - 1]
                    + wx[e].w * Hbuf[hh][sx[e]    ];
        }
        *(float4*)&O[(size_t)hh * NE + x0] = o;
      }
    }
    __syncthreads();
  }
}

// ---------------- host launcher ----------------

extern "C" void kernel_launch(void* const* d_in, const int* in_sizes, int n_in,
                              void* d_out, int out_size, void* d_ws, size_t ws_size,
                              hipStream_t stream) {
  (void)in_sizes; (void)n_in; (void)out_size; (void)ws_size;
  const float* Z = (const float*)d_in[0];
  float* out = (float*)d_out;
  float* S2T = (float*)d_ws;      // 64 MB (must not alias out)

  k_conv1<<<dim3(8, 8, NBC),     256, 0, stream>>>(Z,   S2T);  // contract y + transpose
  k_eval3<<<dim3(NE / YT, NBC),  256, 0, stream>>>(S2T, out);  // y-tiled fused x-band + eval
}

// Round 6
// 141.008 us; speedup vs baseline: 1.5894x; 1.0545x over previous
//
#include <hip/hip_runtime.h>

#define NN  512    // data grid / coefficient count per axis
#define NE  1024   // eval points per axis
#define NBC 64     // batch * channels
#define WH  8      // truncated-inverse half width
#define WT  17     // 2*WH+1 taps
#define YT  16     // y-tile per eval block

// ================= compile-time table generation =================
// Mirrors the reference: x = float32 linspace(-1,1,512); knots via float32
// cumsum sliding mean; basis via de Boor in double; banded LU in double;
// truncated inverse band Gb (half-width 8); and W2a = the x-direction
// COMBINED filter (4-tap eval basis composed with 17-tap Gb), quad-anchored
// at anc = (espan[x0]-11)&~3 so runtime indexing is fully static.

struct Tables {
  float Gb[NN][WT];      // truncated A^-1 band (used by conv1)
  int   espan[NE];
  float ebas[NE * 4];    // y-combine weights (float4-aligned)
  float W2a[NE][28];     // combined x-filter taps, per-quad anchor
};

constexpr int cfindspan(double u, const float* t) {
  if (u >= (double)t[NN]) return NN - 1;          // t[512] == 1.0
  int lo = 3, hi = NN - 1;
  while (lo < hi) {
    int mid = (lo + hi + 1) >> 1;
    if ((double)t[mid] <= u) lo = mid; else hi = mid - 1;
  }
  return lo;
}

constexpr void cdeboor4(double u, const float* t, int s, double* N) {
  double left[4] = {}, right[4] = {};
  N[0] = 1.0; N[1] = 0.0; N[2] = 0.0; N[3] = 0.0;
  for (int d = 1; d <= 3; ++d) {
    left[d]  = u - (double)t[s + 1 - d];
    right[d] = (double)t[s + d] - u;
    double saved = 0.0;
    for (int r = 0; r < d; ++r) {
      double temp = N[r] / (right[r + 1] + left[d - r]);
      N[r] = saved + right[r + 1] * temp;
      saved = left[d - r] * temp;
    }
    N[d] = saved;
  }
}

constexpr Tables make_tables() {
  Tables T{};
  float x[NN] = {};
  for (int i = 0; i < NN; ++i) x[i] = (float)(-1.0 + (2.0 * i) / 511.0);
  x[0] = -1.0f; x[NN - 1] = 1.0f;
  float t[NN + 4] = {};
  {
    float cs[NN + 1] = {};
    for (int i = 0; i < NN; ++i) cs[i + 1] = cs[i] + x[i];
    for (int i = 0; i < NN - 4; ++i) t[4 + i] = (cs[4 + i] - cs[1 + i]) / 3.0f;
    for (int i = 0; i < 4; ++i) { t[i] = -1.0f; t[NN + i] = 1.0f; }
  }
  double W[NN][7] = {};
  for (int r = 0; r < NN; ++r) {
    double u = (double)x[r];
    int s = cfindspan(u, t);
    double N[4] = {};
    cdeboor4(u, t, s, N);
    for (int dd = 0; dd < 4; ++dd) W[r][s - r + dd] += N[dd];
  }
  for (int r = 0; r < NN; ++r) {
    double rd = 1.0 / W[r][3];
    for (int k = 1; k <= 3; ++k) {
      if (r + k < NN) {
        double l = W[r + k][3 - k] * rd;
        W[r + k][3 - k] = l;
        for (int cc = 1; cc <= 3; ++cc) W[r + k][3 - k + cc] -= l * W[r][3 + cc];
      }
    }
  }
  // truncated inverse band (double master copy Gbd + float T.Gb)
  double Gbd[NN][WT] = {};
  double tv[WT] = {};
  for (int pass = 0; pass < 3; ++pass) {
    const int ylo = (pass == 0) ? 0 : (pass == 1) ? 480 : 256;
    const int yhi = (pass == 0) ? 32 : (pass == 1) ? 512 : 257;
    for (int y = ylo; y < yhi; ++y) {
      double wv[21] = {};
      int rend = y + 20; if (rend > NN - 1) rend = NN - 1;
      wv[0] = 1.0;
      for (int r = y + 1; r <= rend; ++r) {
        double acc = 0.0;
        if (r - 1 >= y) acc += W[r][2] * wv[r - 1 - y];
        if (r - 2 >= y) acc += W[r][1] * wv[r - 2 - y];
        if (r - 3 >= y) acc += W[r][0] * wv[r - 3 - y];
        wv[r - y] = -acc;
      }
      double g[29] = {};
      int glo = y - WH; if (glo < 0) glo = 0;
      for (int r = rend; r >= glo; --r) {
        double acc = (r >= y) ? wv[r - y] : 0.0;
        if (r + 1 <= rend) acc -= W[r][4] * g[r + 1 - (y - WH)];
        if (r + 2 <= rend) acc -= W[r][5] * g[r + 2 - (y - WH)];
        if (r + 3 <= rend) acc -= W[r][6] * g[r + 3 - (y - WH)];
        g[r - (y - WH)] = acc / W[r][3];
      }
      if (pass == 2) {
        for (int d = 0; d < WT; ++d) tv[d] = g[16 - d];
      } else {
        int jlo = y - WH; if (jlo < 0) jlo = 0;
        int jhi = y + WH; if (jhi > NN - 1) jhi = NN - 1;
        for (int j = jlo; j <= jhi; ++j) {
          const bool bdry = (pass == 0) ? (j < 24) : (j >= 488);
          if (bdry) Gbd[j][y - j + WH] = g[j - (y - WH)];
        }
      }
    }
  }
  for (int j = 24; j < 488; ++j)
    for (int d = 0; d < WT; ++d) Gbd[j][d] = tv[d];
  for (int j = 0; j < NN; ++j)
    for (int d = 0; d < WT; ++d) T.Gb[j][d] = (float)Gbd[j][d];
  // eval-point basis (keep doubles for W2a composition)
  int    s_all[NE] = {};
  double dN[NE][4] = {};
  for (int i = 0; i < NE; ++i) {
    float xe = (float)(-1.0 + (2.0 * i) / 1023.0);
    if (i == 0) xe = -1.0f;
    if (i == NE - 1) xe = 1.0f;
    double u = (double)xe;
    int s = cfindspan(u, t);
    double N[4] = {};
    cdeboor4(u, t, s, N);
    s_all[i] = s;
    for (int k = 0; k < 4; ++k) dN[i][k] = N[k];
    T.espan[i] = s;
    T.ebas[i * 4 + 0] = (float)N[0];
    T.ebas[i * 4 + 1] = (float)N[1];
    T.ebas[i * 4 + 2] = (float)N[2];
    T.ebas[i * 4 + 3] = (float)N[3];
  }
  // combined x-filter: out[x] = sum_m W2a[x][m] * R[anc + m],
  // anc = (s_all[quad_first]-11) & ~3  (16B-aligned, tap offsets in [0,25])
  for (int xx = 0; xx < NE; ++xx) {
    const int anc = (s_all[(xx >> 2) << 2] - 11) & ~3;
    double acc[28] = {};
    for (int k = 0; k < 4; ++k) {
      const int p = s_all[xx] - 3 + k;
      for (int d = 0; d < WT; ++d) {
        const int i = p - 8 + d;          // R index
        acc[i - anc] += dN[xx][k] * Gbd[p][d];
      }
    }
    for (int m = 0; m < 28; ++m) T.W2a[xx][m] = (float)acc[m];
  }
  return T;
}

__constant__ Tables g_tab = make_tables();

// ------------- K1: contract y (17-tap band), fused transpose -------------
// S2T[bc][j][x] = sum_d Gb[j][d] * Z[bc][x][j-8+d]

__global__ __launch_bounds__(256) void k_conv1(const float* __restrict__ Z,
                                               float* __restrict__ S2T) {
  const int xt = blockIdx.x * 64;
  const int jt = blockIdx.y * 64;
  const int bc = blockIdx.z;
  const float* __restrict__ src = Z + (size_t)bc * (NN * NN);
  __shared__ float in[64][88];   // y-window [jt-8, jt+72)
  __shared__ float tr[64][65];   // transpose buffer (+1 pad)
  const int tid = threadIdx.x;
  const int jqi = tid & 15;
  float c[4][WT];
  #pragma unroll
  for (int q = 0; q < 4; ++q)
    #pragma unroll
    for (int d = 0; d < WT; ++d)
      c[q][d] = g_tab.Gb[jt + jqi * 4 + q][d];
  for (int u = tid; u < 64 * 20; u += 256) {
    const int r = u / 20, c4 = u % 20;
    const int y0 = jt - 8 + c4 * 4;
    float4 v;
    if (y0 >= 0 && y0 + 4 <= NN) {
      v = *(const float4*)&src[(size_t)(xt + r) * NN + y0];
    } else {
      float e0 = (y0 + 0 >= 0 && y0 + 0 < NN) ? src[(size_t)(xt + r) * NN + y0 + 0] : 0.f;
      float e1 = (y0 + 1 >= 0 && y0 + 1 < NN) ? src[(size_t)(xt + r) * NN + y0 + 1] : 0.f;
      float e2 = (y0 + 2 >= 0 && y0 + 2 < NN) ? src[(size_t)(xt + r) * NN + y0 + 2] : 0.f;
      float e3 = (y0 + 3 >= 0 && y0 + 3 < NN) ? src[(size_t)(xt + r) * NN + y0 + 3] : 0.f;
      v = make_float4(e0, e1, e2, e3);
    }
    *(float4*)&in[r][c4 * 4] = v;
  }
  __syncthreads();
  #pragma unroll
  for (int p = 0; p < 4; ++p) {
    const int xl = (tid >> 4) + p * 16;
    float w[20];
    #pragma unroll
    for (int e = 0; e < 5; ++e)
      *(float4*)&w[e * 4] = *(const float4*)&in[xl][jqi * 4 + e * 4];
    float4 a = make_float4(0.f, 0.f, 0.f, 0.f);
    #pragma unroll
    for (int d = 0; d < WT; ++d) {
      a.x += c[0][d] * w[0 + d];
      a.y += c[1][d] * w[1 + d];
      a.z += c[2][d] * w[2 + d];
      a.w += c[3][d] * w[3 + d];
    }
    tr[jqi * 4 + 0][xl] = a.x;
    tr[jqi * 4 + 1][xl] = a.y;
    tr[jqi * 4 + 2][xl] = a.z;
    tr[jqi * 4 + 3][xl] = a.w;
  }
  __syncthreads();
  float* __restrict__ dst = S2T + (size_t)bc * (NN * NN);
  for (int u = tid; u < 64 * 16; u += 256) {
    const int jr = u >> 4, x4 = (u & 15) * 4;
    float4 v = make_float4(tr[jr][x4 + 0], tr[jr][x4 + 1], tr[jr][x4 + 2], tr[jr][x4 + 3]);
    *(float4*)&dst[(size_t)(jt + jr) * NN + xt + x4] = v;
  }
}

// ------------- K2: y-tiled eval with combined 28-tap x-filter -------------
// Per block: 16 output rows. rows window loaded once; per y-pair:
//   R[x] = 4-row combine (both rows)  ->  out[x] = 28-tap static dot on R.
// One barrier per pair (double-buffered Rbuf). All register indexing static.

__global__ __launch_bounds__(256) void k_eval4(const float* __restrict__ S2T,
                                               float* __restrict__ out) {
  const int y0 = blockIdx.x * YT;
  const int bc = blockIdx.y;
  const float* __restrict__ S = S2T + (size_t)bc * (NN * NN);
  __shared__ float rows[16][NN];                 // 32 KB row window
  __shared__ __align__(16) float Rb[2][2][544];  // [dbuf][row-of-pair][12+x], halo zeros
  const int tid = threadIdx.x;
  const int rlo = g_tab.espan[y0] - 3;

  // cooperative load of 16 rows (contiguous 32 KB of S2T)
  for (int u = tid; u < 16 * 128; u += 256) {
    const int rr = u >> 7, c4 = (u & 127) * 4;
    const int r = rlo + rr;
    float4 v = (r < NN) ? *(const float4*)&S[(size_t)r * NN + c4]
                        : make_float4(0.f, 0.f, 0.f, 0.f);
    *(float4*)&rows[rr][c4] = v;
  }
  if (tid < 128) {   // zero halos [0..11] and [524..543] of all 4 R rows
    const int b = tid >> 5, o = tid & 31;
    const int idx = (o < 12) ? o : (512 + o);    // 524..543
    Rb[b >> 1][b & 1][idx] = 0.f;
  }

  // hoisted per-thread constants: x-quad taps + anchor
  const int x0 = tid * 4;
  const int anc = (g_tab.espan[x0] - 11) & ~3;   // multiple of 4, >= -8
  float tp[4][28];
  #pragma unroll
  for (int e = 0; e < 4; ++e)
    #pragma unroll
    for (int m = 0; m < 28; ++m)
      tp[e][m] = g_tab.W2a[x0 + e][m];
  const int p2 = tid * 2;

  auto do_R = [&](int k) {
    const int buf = k & 1;
    #pragma unroll
    for (int hh = 0; hh < 2; ++hh) {
      const int y = y0 + 2 * k + hh;
      const int ry = g_tab.espan[y] - rlo;       // 3..15 by construction
      const float4 wy = *(const float4*)&g_tab.ebas[y * 4];
      float2 r0 = *(const float2*)&rows[ry - 3][p2];
      float2 r1 = *(const float2*)&rows[ry - 2][p2];
      float2 r2 = *(const float2*)&rows[ry - 1][p2];
      float2 r3 = *(const float2*)&rows[ry    ][p2];
      float2 acc;
      acc.x = wy.x * r0.x + wy.y * r1.x + wy.z * r2.x + wy.w * r3.x;
      acc.y = wy.x * r0.y + wy.y * r1.y + wy.z * r2.y + wy.w * r3.y;
      *(float2*)&Rb[buf][hh][12 + p2] = acc;
    }
  };

  __syncthreads();
  do_R(0);
  __syncthreads();
  #pragma unroll 1
  for (int k = 0; k < YT / 2; ++k) {
    if (k + 1 < YT / 2) do_R(k + 1);             // fill other buffer
    float* __restrict__ O = out + ((size_t)bc * NE + (y0 + 2 * k)) * NE;
    #pragma unroll
    for (int hh = 0; hh < 2; ++hh) {
      const float* __restrict__ Rw = &Rb[k & 1][hh][12 + anc];  // 16B-aligned
      float w[28];
      #pragma unroll
      for (int e = 0; e < 7; ++e)
        *(float4*)&w[e * 4] = *(const float4*)&Rw[e * 4];
      float4 o;
      #pragma unroll
      for (int e = 0; e < 4; ++e) {
        float a0 = 0.f, a1 = 0.f;
        #pragma unroll
        for (int m = 0; m < 28; m += 2) {
          a0 += tp[e][m]     * w[m];
          a1 += tp[e][m + 1] * w[m + 1];
        }
        (&o.x)[e] = a0 + a1;
      }
      *(float4*)&O[(size_t)hh * NE + x0] = o;
    }
    __syncthreads();
  }
}

// ---------------- host launcher ----------------

extern "C" void kernel_launch(void* const* d_in, const int* in_sizes, int n_in,
                              void* d_out, int out_size, void* d_ws, size_t ws_size,
                              hipStream_t stream) {
  (void)in_sizes; (void)n_in; (void)out_size; (void)ws_size;
  const float* Z = (const float*)d_in[0];
  float* out = (float*)d_out;
  float* S2T = (float*)d_ws;      // 64 MB (must not alias out)

  k_conv1<<<dim3(8, 8, NBC),    256, 0, stream>>>(Z,   S2T);  // contract y + transpose
  k_eval4<<<dim3(NE / YT, NBC), 256, 0, stream>>>(S2T, out);  // combined-tap eval
}